// Round 2
// baseline (946.017 us; speedup 1.0000x reference)
//
#include <hip/hip_runtime.h>
#include <math.h>

#define NEGV (-1000.0f)
#define SLOPE 0.01f
#define D_IN 256
#define KC 32
#define HS_PAD 36

// ---------- W transpose: W[h][k][f] -> Wt[k][f][h] ----------
__global__ void wt_kernel(const float* __restrict__ W, float* __restrict__ Wt) {
    int i = blockIdx.x * 256 + threadIdx.x;   // 65536 elems, input-coalesced
    int f = i & 63;
    int k = (i >> 6) & 255;
    int h = i >> 14;
    Wt[(k * 64 + f) * 4 + h] = W[i];
}

// ---------- GEMM: z_t[n][f][h] = sum_k h[n][k] * Wt[k][f][h] ----------
__global__ __launch_bounds__(256) void gemm_kernel(const float* __restrict__ hmat,
                                                   const float* __restrict__ Wt,
                                                   float* __restrict__ z_t, int N) {
    __shared__ float wS[KC * 256];        // [kk][f][h], float4 idx = kk*64+f
    __shared__ float hS[64 * HS_PAD];     // [row][kk], pad 36 keeps b128 align
    const int t = threadIdx.x;
    const int lane = t & 63;              // = f
    const int trow = t >> 6;              // wave id -> rows trow*16..+15
    const int n0 = blockIdx.x * 64;

    float4 acc[16];
#pragma unroll
    for (int r = 0; r < 16; r++) acc[r] = make_float4(0.f, 0.f, 0.f, 0.f);

    for (int k0 = 0; k0 < D_IN; k0 += KC) {
        __syncthreads();
        // stage W chunk: straight 32KB copy (contiguous in Wt layout)
        const float4* Wg = (const float4*)(Wt + (size_t)k0 * 256);
        float4* wS4 = (float4*)wS;
#pragma unroll
        for (int i = 0; i < 8; i++) wS4[t + i * 256] = Wg[t + i * 256];
        // stage h chunk: 64 rows x 32 k
#pragma unroll
        for (int i = 0; i < 2; i++) {
            int idx4 = t + i * 256;       // 0..511
            int kk4 = idx4 & 7;
            int row = idx4 >> 3;
            int n = n0 + row;
            float4 v = make_float4(0.f, 0.f, 0.f, 0.f);
            if (n < N) v = *(const float4*)&hmat[(size_t)n * D_IN + k0 + kk4 * 4];
            *(float4*)&hS[row * HS_PAD + kk4 * 4] = v;
        }
        __syncthreads();
#pragma unroll
        for (int s = 0; s < 8; s++) {
            float4 wv0 = *(const float4*)&wS[((s * 4 + 0) * 64 + lane) * 4];
            float4 wv1 = *(const float4*)&wS[((s * 4 + 1) * 64 + lane) * 4];
            float4 wv2 = *(const float4*)&wS[((s * 4 + 2) * 64 + lane) * 4];
            float4 wv3 = *(const float4*)&wS[((s * 4 + 3) * 64 + lane) * 4];
#pragma unroll
            for (int r = 0; r < 16; r++) {
                float4 hb = *(const float4*)&hS[(trow * 16 + r) * HS_PAD + s * 4];
                acc[r].x += hb.x * wv0.x; acc[r].y += hb.x * wv0.y;
                acc[r].z += hb.x * wv0.z; acc[r].w += hb.x * wv0.w;
                acc[r].x += hb.y * wv1.x; acc[r].y += hb.y * wv1.y;
                acc[r].z += hb.y * wv1.z; acc[r].w += hb.y * wv1.w;
                acc[r].x += hb.z * wv2.x; acc[r].y += hb.z * wv2.y;
                acc[r].z += hb.z * wv2.z; acc[r].w += hb.z * wv2.w;
                acc[r].x += hb.w * wv3.x; acc[r].y += hb.w * wv3.y;
                acc[r].z += hb.w * wv3.z; acc[r].w += hb.w * wv3.w;
            }
        }
    }
#pragma unroll
    for (int r = 0; r < 16; r++) {
        int n = n0 + trow * 16 + r;
        if (n < N) *(float4*)&z_t[(size_t)n * 256 + lane * 4] = acc[r];
    }
}

// ---------- es/ed per node: es_ed[n][0..3]=es, [4..7]=ed ----------
__global__ void esed_kernel(const float* __restrict__ z_t, const float* __restrict__ att,
                            float* __restrict__ es_ed, int N) {
    int gid = blockIdx.x * blockDim.x + threadIdx.x;
    int n = gid >> 6;
    int lane = gid & 63;
    if (n >= N) return;
    float4 zv = *(const float4*)&z_t[(size_t)n * 256 + lane * 4];
    float ps0 = zv.x * att[0 * 128 + lane];
    float ps1 = zv.y * att[1 * 128 + lane];
    float ps2 = zv.z * att[2 * 128 + lane];
    float ps3 = zv.w * att[3 * 128 + lane];
    float pd0 = zv.x * att[0 * 128 + 64 + lane];
    float pd1 = zv.y * att[1 * 128 + 64 + lane];
    float pd2 = zv.z * att[2 * 128 + 64 + lane];
    float pd3 = zv.w * att[3 * 128 + 64 + lane];
    for (int off = 1; off < 64; off <<= 1) {
        ps0 += __shfl_xor(ps0, off); ps1 += __shfl_xor(ps1, off);
        ps2 += __shfl_xor(ps2, off); ps3 += __shfl_xor(ps3, off);
        pd0 += __shfl_xor(pd0, off); pd1 += __shfl_xor(pd1, off);
        pd2 += __shfl_xor(pd2, off); pd3 += __shfl_xor(pd3, off);
    }
    if (lane == 0) {
        *(float4*)&es_ed[(size_t)n * 8]     = make_float4(ps0, ps1, ps2, ps3);
        *(float4*)&es_ed[(size_t)n * 8 + 4] = make_float4(pd0, pd1, pd2, pd3);
    }
}

// ---------- CSR build ----------
__global__ void hist_kernel(const int* __restrict__ dst, int* __restrict__ counts, int E) {
    int i = blockIdx.x * blockDim.x + threadIdx.x;
    if (i < E) atomicAdd(&counts[dst[i]], 1);
}

__global__ void scan_kernel(const int* __restrict__ counts, int* __restrict__ row_start, int N) {
    __shared__ int sums[1024];
    int t = threadIdx.x;
    int per = (N + 1023) >> 10;
    int lo = t * per;
    int hi = min(lo + per, N);
    int s = 0;
    for (int i = lo; i < hi; i++) s += counts[i];
    sums[t] = s;
    __syncthreads();
    for (int off = 1; off < 1024; off <<= 1) {
        int v = (t >= off) ? sums[t - off] : 0;
        __syncthreads();
        sums[t] += v;
        __syncthreads();
    }
    int run = sums[t] - s;   // exclusive base for this thread's chunk
    for (int i = lo; i < hi; i++) { row_start[i] = run; run += counts[i]; }
}

__global__ void scatter_kernel(const int* __restrict__ src, const int* __restrict__ dst,
                               const int* __restrict__ row_start, int* __restrict__ cursor,
                               int* __restrict__ csr_src, int E) {
    int i = blockIdx.x * blockDim.x + threadIdx.x;
    if (i < E) {
        int d = dst[i];
        int pos = row_start[d] + atomicAdd(&cursor[d], 1);
        csr_src[pos] = src[i];
    }
}

// ---------- aggregation: one wave per node ----------
__global__ __launch_bounds__(256) void aggregate_kernel(const float* __restrict__ z_t,
        const float* __restrict__ es_ed, const int* __restrict__ csr_src,
        const int* __restrict__ row_start, const int* __restrict__ counts,
        float* __restrict__ out, int N) {
    int gid = blockIdx.x * blockDim.x + threadIdx.x;
    int n = gid >> 6;
    int lane = gid & 63;   // = f
    if (n >= N) return;
    int cnt = counts[n];
    int start = row_start[n];
    float4 edn = *(const float4*)&es_ed[(size_t)n * 8 + 4];

    float m0 = -INFINITY, m1 = -INFINITY, m2 = -INFINITY, m3 = -INFINITY;
    for (int base = 0; base < cnt; base += 64) {
        int i = base + lane;
        float e0 = -INFINITY, e1 = -INFINITY, e2 = -INFINITY, e3 = -INFINITY;
        if (i < cnt) {
            int s = csr_src[start + i];
            float4 esv = *(const float4*)&es_ed[(size_t)s * 8];
            float x0 = esv.x + edn.x; e0 = x0 > 0.f ? x0 : SLOPE * x0; if (e0 == 0.f) e0 = NEGV;
            float x1 = esv.y + edn.y; e1 = x1 > 0.f ? x1 : SLOPE * x1; if (e1 == 0.f) e1 = NEGV;
            float x2 = esv.z + edn.z; e2 = x2 > 0.f ? x2 : SLOPE * x2; if (e2 == 0.f) e2 = NEGV;
            float x3 = esv.w + edn.w; e3 = x3 > 0.f ? x3 : SLOPE * x3; if (e3 == 0.f) e3 = NEGV;
        }
        m0 = fmaxf(m0, e0); m1 = fmaxf(m1, e1); m2 = fmaxf(m2, e2); m3 = fmaxf(m3, e3);
    }
    for (int off = 1; off < 64; off <<= 1) {
        m0 = fmaxf(m0, __shfl_xor(m0, off)); m1 = fmaxf(m1, __shfl_xor(m1, off));
        m2 = fmaxf(m2, __shfl_xor(m2, off)); m3 = fmaxf(m3, __shfl_xor(m3, off));
    }

    float l0 = 0.f, l1 = 0.f, l2 = 0.f, l3 = 0.f;
    float4 o = make_float4(0.f, 0.f, 0.f, 0.f);
    for (int base = 0; base < cnt; base += 64) {
        int c = min(64, cnt - base);
        int i = base + lane;
        int s = 0;
        float p0 = 0.f, p1 = 0.f, p2 = 0.f, p3 = 0.f;
        if (i < cnt) {
            s = csr_src[start + i];
            float4 esv = *(const float4*)&es_ed[(size_t)s * 8];
            float x0 = esv.x + edn.x; float e0 = x0 > 0.f ? x0 : SLOPE * x0; if (e0 == 0.f) e0 = NEGV;
            float x1 = esv.y + edn.y; float e1 = x1 > 0.f ? x1 : SLOPE * x1; if (e1 == 0.f) e1 = NEGV;
            float x2 = esv.z + edn.z; float e2 = x2 > 0.f ? x2 : SLOPE * x2; if (e2 == 0.f) e2 = NEGV;
            float x3 = esv.w + edn.w; float e3 = x3 > 0.f ? x3 : SLOPE * x3; if (e3 == 0.f) e3 = NEGV;
            p0 = __expf(e0 - m0); p1 = __expf(e1 - m1);
            p2 = __expf(e2 - m2); p3 = __expf(e3 - m3);
        }
        l0 += p0; l1 += p1; l2 += p2; l3 += p3;
        int j = 0;
        for (; j + 3 < c; j += 4) {
            int sa = __shfl(s, j), sb = __shfl(s, j + 1), sc = __shfl(s, j + 2), sd = __shfl(s, j + 3);
            float qa0 = __shfl(p0, j),     qa1 = __shfl(p1, j),     qa2 = __shfl(p2, j),     qa3 = __shfl(p3, j);
            float qb0 = __shfl(p0, j + 1), qb1 = __shfl(p1, j + 1), qb2 = __shfl(p2, j + 1), qb3 = __shfl(p3, j + 1);
            float qc0 = __shfl(p0, j + 2), qc1 = __shfl(p1, j + 2), qc2 = __shfl(p2, j + 2), qc3 = __shfl(p3, j + 2);
            float qd0 = __shfl(p0, j + 3), qd1 = __shfl(p1, j + 3), qd2 = __shfl(p2, j + 3), qd3 = __shfl(p3, j + 3);
            float4 za = *(const float4*)&z_t[(size_t)sa * 256 + lane * 4];
            float4 zb = *(const float4*)&z_t[(size_t)sb * 256 + lane * 4];
            float4 zc = *(const float4*)&z_t[(size_t)sc * 256 + lane * 4];
            float4 zd = *(const float4*)&z_t[(size_t)sd * 256 + lane * 4];
            o.x += qa0 * za.x; o.y += qa1 * za.y; o.z += qa2 * za.z; o.w += qa3 * za.w;
            o.x += qb0 * zb.x; o.y += qb1 * zb.y; o.z += qb2 * zb.z; o.w += qb3 * zb.w;
            o.x += qc0 * zc.x; o.y += qc1 * zc.y; o.z += qc2 * zc.z; o.w += qc3 * zc.w;
            o.x += qd0 * zd.x; o.y += qd1 * zd.y; o.z += qd2 * zd.z; o.w += qd3 * zd.w;
        }
        for (; j < c; ++j) {
            int sj = __shfl(s, j);
            float q0 = __shfl(p0, j), q1 = __shfl(p1, j), q2 = __shfl(p2, j), q3 = __shfl(p3, j);
            float4 zv = *(const float4*)&z_t[(size_t)sj * 256 + lane * 4];
            o.x += q0 * zv.x; o.y += q1 * zv.y; o.z += q2 * zv.z; o.w += q3 * zv.w;
        }
    }
    for (int off = 1; off < 64; off <<= 1) {
        l0 += __shfl_xor(l0, off); l1 += __shfl_xor(l1, off);
        l2 += __shfl_xor(l2, off); l3 += __shfl_xor(l3, off);
    }
    if (cnt > 0) { o.x /= l0; o.y /= l1; o.z /= l2; o.w /= l3; }
    size_t ob = (size_t)n * 256;
    out[ob + lane]       = o.x;
    out[ob + 64 + lane]  = o.y;
    out[ob + 128 + lane] = o.z;
    out[ob + 192 + lane] = o.w;
}

extern "C" void kernel_launch(void* const* d_in, const int* in_sizes, int n_in,
                              void* d_out, int out_size, void* d_ws, size_t ws_size,
                              hipStream_t stream) {
    const float* hmat = (const float*)d_in[0];
    const float* W    = (const float*)d_in[1];
    const float* att  = (const float*)d_in[2];
    const int*   src  = (const int*)d_in[3];
    const int*   dst  = (const int*)d_in[4];
    int N = in_sizes[0] / D_IN;
    int E = in_sizes[3];
    float* out = (float*)d_out;

    // workspace layout (all 16B-aligned); total ~114 MB
    float* z_t      = (float*)d_ws;                 // N*256 floats
    float* es_ed    = z_t + (size_t)N * 256;        // N*8
    float* Wt       = es_ed + (size_t)N * 8;        // 65536
    int*   counts   = (int*)(Wt + 65536);           // N
    int*   cursor   = counts + N;                   // N (contiguous with counts)
    int*   row_start= cursor + N;                   // N
    int*   csr_src  = row_start + N;                // E

    hipMemsetAsync(counts, 0, (size_t)2 * N * sizeof(int), stream);
    wt_kernel<<<256, 256, 0, stream>>>(W, Wt);
    gemm_kernel<<<(N + 63) / 64, 256, 0, stream>>>(hmat, Wt, z_t, N);
    esed_kernel<<<(N * 64 + 255) / 256, 256, 0, stream>>>(z_t, att, es_ed, N);
    hist_kernel<<<(E + 255) / 256, 256, 0, stream>>>(dst, counts, E);
    scan_kernel<<<1, 1024, 0, stream>>>(counts, row_start, N);
    scatter_kernel<<<(E + 255) / 256, 256, 0, stream>>>(src, dst, row_start, cursor, csr_src, E);
    aggregate_kernel<<<(N * 64 + 255) / 256, 256, 0, stream>>>(z_t, es_ed, csr_src, row_start, counts, out, N);
}

// Round 3
// 802.238 us; speedup vs baseline: 1.1792x; 1.1792x over previous
//
#include <hip/hip_runtime.h>
#include <math.h>

#define NEGV (-1000.0f)
#define SLOPE 0.01f
#define D_IN 256
#define KC 32

// async global->LDS, 16B per lane; lds base must be wave-uniform (HW adds lane*16)
#define GLOAD_LDS16(g, l) \
    __builtin_amdgcn_global_load_lds((const __attribute__((address_space(1))) unsigned int*)(g), \
                                     (__attribute__((address_space(3))) unsigned int*)(l), 16, 0, 0)

// ---------- W transpose: W[h][k][f] -> Wt[k][f][h] ----------
__global__ void wt_kernel(const float* __restrict__ W, float* __restrict__ Wt) {
    int i = blockIdx.x * 256 + threadIdx.x;   // 65536 elems, input-coalesced
    int f = i & 63;
    int k = (i >> 6) & 255;
    int h = i >> 14;
    Wt[(k * 64 + f) * 4 + h] = W[i];
}

// ---------- GEMM: z_t[n][f][h] = sum_k h[n][k] * Wt[k][f][h] ----------
// 512 threads, 128 rows/block, 16 rows/thread; global_load_lds staging.
__global__ __launch_bounds__(512) void gemm_kernel(const float* __restrict__ hmat,
                                                   const float* __restrict__ Wt,
                                                   float* __restrict__ z_t, int N) {
    __shared__ float wS[KC * 256];        // [kk][f][h] as float4 idx kk*64+f (32 KB)
    __shared__ float hS[128 * 32];        // [row][kk] unpadded (16 KB): hb reads are broadcasts
    const int t = threadIdx.x;
    const int lane = t & 63;              // = f
    const int w = t >> 6;                 // wave 0..7 -> rows w*16..+15
    const int n0 = blockIdx.x * 128;

    float4 acc[16];
#pragma unroll
    for (int r = 0; r < 16; r++) acc[r] = make_float4(0.f, 0.f, 0.f, 0.f);

    for (int k0 = 0; k0 < D_IN; k0 += KC) {
        __syncthreads();
        // stage W chunk (2048 float4): per wave-iter, uniform LDS base + lane*16
        const float4* Wg = (const float4*)(Wt + (size_t)k0 * 256);
        float4* wS4 = (float4*)wS;
        float4* hS4 = (float4*)hS;
#pragma unroll
        for (int i = 0; i < 4; i++) {
            int f4 = i * 512 + t;                       // per-lane global index
            GLOAD_LDS16(Wg + f4, wS4 + i * 512 + w * 64); // base uniform per wave
        }
        // stage h chunk (1024 float4): 128 rows x 8 float4
#pragma unroll
        for (int i = 0; i < 2; i++) {
            int f4 = i * 512 + t;
            int row = f4 >> 3;
            int kk4 = f4 & 7;
            if (n0 + row < N)
                GLOAD_LDS16(&hmat[(size_t)(n0 + row) * D_IN + k0 + kk4 * 4],
                            hS4 + i * 512 + w * 64);
        }
        __syncthreads();
#pragma unroll
        for (int s = 0; s < 8; s++) {
            float4 wv0 = *(const float4*)&wS[((s * 4 + 0) * 64 + lane) * 4];
            float4 wv1 = *(const float4*)&wS[((s * 4 + 1) * 64 + lane) * 4];
            float4 wv2 = *(const float4*)&wS[((s * 4 + 2) * 64 + lane) * 4];
            float4 wv3 = *(const float4*)&wS[((s * 4 + 3) * 64 + lane) * 4];
#pragma unroll
            for (int r = 0; r < 16; r++) {
                float4 hb = *(const float4*)&hS[(w * 16 + r) * 32 + s * 4];
                acc[r].x += hb.x * wv0.x; acc[r].y += hb.x * wv0.y;
                acc[r].z += hb.x * wv0.z; acc[r].w += hb.x * wv0.w;
                acc[r].x += hb.y * wv1.x; acc[r].y += hb.y * wv1.y;
                acc[r].z += hb.y * wv1.z; acc[r].w += hb.y * wv1.w;
                acc[r].x += hb.z * wv2.x; acc[r].y += hb.z * wv2.y;
                acc[r].z += hb.z * wv2.z; acc[r].w += hb.z * wv2.w;
                acc[r].x += hb.w * wv3.x; acc[r].y += hb.w * wv3.y;
                acc[r].z += hb.w * wv3.z; acc[r].w += hb.w * wv3.w;
            }
        }
    }
#pragma unroll
    for (int r = 0; r < 16; r++) {
        int n = n0 + w * 16 + r;
        if (n < N) *(float4*)&z_t[(size_t)n * 256 + lane * 4] = acc[r];
    }
}

// ---------- es/ed per node ----------
__global__ void esed_kernel(const float* __restrict__ z_t, const float* __restrict__ att,
                            float* __restrict__ es_ed, int N) {
    int gid = blockIdx.x * blockDim.x + threadIdx.x;
    int n = gid >> 6;
    int lane = gid & 63;
    if (n >= N) return;
    float4 zv = *(const float4*)&z_t[(size_t)n * 256 + lane * 4];
    float ps0 = zv.x * att[0 * 128 + lane];
    float ps1 = zv.y * att[1 * 128 + lane];
    float ps2 = zv.z * att[2 * 128 + lane];
    float ps3 = zv.w * att[3 * 128 + lane];
    float pd0 = zv.x * att[0 * 128 + 64 + lane];
    float pd1 = zv.y * att[1 * 128 + 64 + lane];
    float pd2 = zv.z * att[2 * 128 + 64 + lane];
    float pd3 = zv.w * att[3 * 128 + 64 + lane];
    for (int off = 1; off < 64; off <<= 1) {
        ps0 += __shfl_xor(ps0, off); ps1 += __shfl_xor(ps1, off);
        ps2 += __shfl_xor(ps2, off); ps3 += __shfl_xor(ps3, off);
        pd0 += __shfl_xor(pd0, off); pd1 += __shfl_xor(pd1, off);
        pd2 += __shfl_xor(pd2, off); pd3 += __shfl_xor(pd3, off);
    }
    if (lane == 0) {
        *(float4*)&es_ed[(size_t)n * 8]     = make_float4(ps0, ps1, ps2, ps3);
        *(float4*)&es_ed[(size_t)n * 8 + 4] = make_float4(pd0, pd1, pd2, pd3);
    }
}

// ---------- CSR build ----------
__global__ void hist_kernel(const int* __restrict__ dst, int* __restrict__ counts, int E) {
    int i = blockIdx.x * blockDim.x + threadIdx.x;
    if (i < E) atomicAdd(&counts[dst[i]], 1);
}

// 3-phase scan: A=block reduce, B=scan of block sums, C=block scan + add offset
__global__ void scanA_kernel(const int* __restrict__ counts, int* __restrict__ bsums, int N) {
    __shared__ int lds[256];
    int t = threadIdx.x;
    int base = blockIdx.x * 1024 + t * 4;
    int s = 0;
    if (base + 3 < N) {
        int4 v = *(const int4*)&counts[base];
        s = v.x + v.y + v.z + v.w;
    } else {
        for (int u = 0; u < 4; u++) if (base + u < N) s += counts[base + u];
    }
    lds[t] = s; __syncthreads();
    for (int off = 128; off > 0; off >>= 1) {
        if (t < off) lds[t] += lds[t + off];
        __syncthreads();
    }
    if (t == 0) bsums[blockIdx.x] = lds[0];
}

__global__ void scanB_kernel(int* __restrict__ bsums, int nb) {
    __shared__ int lds[256];
    int t = threadIdx.x;
    int v = (t < nb) ? bsums[t] : 0;
    lds[t] = v; __syncthreads();
    for (int off = 1; off < 256; off <<= 1) {
        int x = (t >= off) ? lds[t - off] : 0;
        __syncthreads();
        lds[t] += x;
        __syncthreads();
    }
    if (t < nb) bsums[t] = lds[t] - v;   // exclusive
}

__global__ void scanC_kernel(const int* __restrict__ counts, const int* __restrict__ bsums,
                             int* __restrict__ row_start, int N) {
    __shared__ int lds[256];
    int t = threadIdx.x;
    int base = blockIdx.x * 1024 + t * 4;
    int4 v = make_int4(0, 0, 0, 0);
    if (base + 3 < N) v = *(const int4*)&counts[base];
    else {
        if (base + 0 < N) v.x = counts[base + 0];
        if (base + 1 < N) v.y = counts[base + 1];
        if (base + 2 < N) v.z = counts[base + 2];
    }
    int s = v.x + v.y + v.z + v.w;
    lds[t] = s; __syncthreads();
    for (int off = 1; off < 256; off <<= 1) {
        int x = (t >= off) ? lds[t - off] : 0;
        __syncthreads();
        lds[t] += x;
        __syncthreads();
    }
    int excl = lds[t] - s + bsums[blockIdx.x];
    int4 r;
    r.x = excl; r.y = r.x + v.x; r.z = r.y + v.y; r.w = r.z + v.z;
    if (base + 3 < N) *(int4*)&row_start[base] = r;
    else {
        if (base + 0 < N) row_start[base + 0] = r.x;
        if (base + 1 < N) row_start[base + 1] = r.y;
        if (base + 2 < N) row_start[base + 2] = r.z;
    }
}

__global__ void scatter_kernel(const int* __restrict__ src, const int* __restrict__ dst,
                               const int* __restrict__ row_start, int* __restrict__ cursor,
                               int* __restrict__ csr_src, int E) {
    int i = blockIdx.x * blockDim.x + threadIdx.x;
    if (i < E) {
        int d = dst[i];
        int pos = row_start[d] + atomicAdd(&cursor[d], 1);
        csr_src[pos] = src[i];
    }
}

// ---------- aggregation: one wave per node, single-pass online softmax ----------
__global__ __launch_bounds__(256) void aggregate_kernel(const float* __restrict__ z_t,
        const float* __restrict__ es_ed, const int* __restrict__ csr_src,
        const int* __restrict__ row_start, const int* __restrict__ counts,
        float* __restrict__ out, int N) {
    int gid = blockIdx.x * blockDim.x + threadIdx.x;
    int n = gid >> 6;
    int lane = gid & 63;   // = f
    if (n >= N) return;
    int cnt = counts[n];
    int start = row_start[n];
    float4 edn = *(const float4*)&es_ed[(size_t)n * 8 + 4];

    float m0 = -INFINITY, m1 = -INFINITY, m2 = -INFINITY, m3 = -INFINITY;
    float l0 = 0.f, l1 = 0.f, l2 = 0.f, l3 = 0.f;
    float4 o = make_float4(0.f, 0.f, 0.f, 0.f);

    for (int base = 0; base < cnt; base += 64) {
        int c = min(64, cnt - base);
        int i = base + lane;
        int s = 0;
        float e0 = -INFINITY, e1 = -INFINITY, e2 = -INFINITY, e3 = -INFINITY;
        if (i < cnt) {
            s = csr_src[start + i];
            float4 esv = *(const float4*)&es_ed[(size_t)s * 8];
            float x0 = esv.x + edn.x; e0 = x0 > 0.f ? x0 : SLOPE * x0; if (e0 == 0.f) e0 = NEGV;
            float x1 = esv.y + edn.y; e1 = x1 > 0.f ? x1 : SLOPE * x1; if (e1 == 0.f) e1 = NEGV;
            float x2 = esv.z + edn.z; e2 = x2 > 0.f ? x2 : SLOPE * x2; if (e2 == 0.f) e2 = NEGV;
            float x3 = esv.w + edn.w; e3 = x3 > 0.f ? x3 : SLOPE * x3; if (e3 == 0.f) e3 = NEGV;
        }
        // chunk max across the wave (uniform result)
        float c0 = e0, c1 = e1, c2 = e2, c3 = e3;
        for (int off = 1; off < 64; off <<= 1) {
            c0 = fmaxf(c0, __shfl_xor(c0, off)); c1 = fmaxf(c1, __shfl_xor(c1, off));
            c2 = fmaxf(c2, __shfl_xor(c2, off)); c3 = fmaxf(c3, __shfl_xor(c3, off));
        }
        float nm0 = fmaxf(m0, c0), nm1 = fmaxf(m1, c1), nm2 = fmaxf(m2, c2), nm3 = fmaxf(m3, c3);
        float sc0 = __expf(m0 - nm0), sc1 = __expf(m1 - nm1);
        float sc2 = __expf(m2 - nm2), sc3 = __expf(m3 - nm3);   // exp(-inf)=0 on first chunk
        o.x *= sc0; o.y *= sc1; o.z *= sc2; o.w *= sc3;
        l0 *= sc0; l1 *= sc1; l2 *= sc2; l3 *= sc3;
        m0 = nm0; m1 = nm1; m2 = nm2; m3 = nm3;

        float p0 = 0.f, p1 = 0.f, p2 = 0.f, p3 = 0.f;
        if (i < cnt) {
            p0 = __expf(e0 - m0); p1 = __expf(e1 - m1);
            p2 = __expf(e2 - m2); p3 = __expf(e3 - m3);
        }
        l0 += p0; l1 += p1; l2 += p2; l3 += p3;

        int j = 0;
        for (; j + 7 < c; j += 8) {
            float4 pp[8]; float4 zz[8];
#pragma unroll
            for (int u = 0; u < 8; u++) {
                int sj = __shfl(s, j + u);
                pp[u] = make_float4(__shfl(p0, j + u), __shfl(p1, j + u),
                                    __shfl(p2, j + u), __shfl(p3, j + u));
                zz[u] = *(const float4*)&z_t[(size_t)sj * 256 + lane * 4];
            }
#pragma unroll
            for (int u = 0; u < 8; u++) {
                o.x += pp[u].x * zz[u].x; o.y += pp[u].y * zz[u].y;
                o.z += pp[u].z * zz[u].z; o.w += pp[u].w * zz[u].w;
            }
        }
        for (; j < c; ++j) {
            int sj = __shfl(s, j);
            float q0 = __shfl(p0, j), q1 = __shfl(p1, j), q2 = __shfl(p2, j), q3 = __shfl(p3, j);
            float4 zv = *(const float4*)&z_t[(size_t)sj * 256 + lane * 4];
            o.x += q0 * zv.x; o.y += q1 * zv.y; o.z += q2 * zv.z; o.w += q3 * zv.w;
        }
    }
    for (int off = 1; off < 64; off <<= 1) {
        l0 += __shfl_xor(l0, off); l1 += __shfl_xor(l1, off);
        l2 += __shfl_xor(l2, off); l3 += __shfl_xor(l3, off);
    }
    if (cnt > 0) { o.x /= l0; o.y /= l1; o.z /= l2; o.w /= l3; }
    size_t ob = (size_t)n * 256;
    __builtin_nontemporal_store(o.x, &out[ob + lane]);
    __builtin_nontemporal_store(o.y, &out[ob + 64 + lane]);
    __builtin_nontemporal_store(o.z, &out[ob + 128 + lane]);
    __builtin_nontemporal_store(o.w, &out[ob + 192 + lane]);
}

extern "C" void kernel_launch(void* const* d_in, const int* in_sizes, int n_in,
                              void* d_out, int out_size, void* d_ws, size_t ws_size,
                              hipStream_t stream) {
    const float* hmat = (const float*)d_in[0];
    const float* W    = (const float*)d_in[1];
    const float* att  = (const float*)d_in[2];
    const int*   src  = (const int*)d_in[3];
    const int*   dst  = (const int*)d_in[4];
    int N = in_sizes[0] / D_IN;
    int E = in_sizes[3];
    float* out = (float*)d_out;

    // workspace layout (all 16B-aligned); total ~114 MB
    float* z_t      = (float*)d_ws;                 // N*256 floats
    float* es_ed    = z_t + (size_t)N * 256;        // N*8
    float* Wt       = es_ed + (size_t)N * 8;        // 65536
    int*   counts   = (int*)(Wt + 65536);           // N
    int*   cursor   = counts + N;                   // N (contiguous with counts)
    int*   row_start= cursor + N;                   // N
    int*   bsums    = row_start + N;                // <=256
    int*   csr_src  = bsums + 256;                  // E

    int NB = (N + 1023) / 1024;

    hipMemsetAsync(counts, 0, (size_t)2 * N * sizeof(int), stream);
    wt_kernel<<<256, 256, 0, stream>>>(W, Wt);
    gemm_kernel<<<(N + 127) / 128, 512, 0, stream>>>(hmat, Wt, z_t, N);
    esed_kernel<<<(N * 64 + 255) / 256, 256, 0, stream>>>(z_t, att, es_ed, N);
    hist_kernel<<<(E + 255) / 256, 256, 0, stream>>>(dst, counts, E);
    scanA_kernel<<<NB, 256, 0, stream>>>(counts, bsums, N);
    scanB_kernel<<<1, 256, 0, stream>>>(bsums, NB);
    scanC_kernel<<<NB, 256, 0, stream>>>(counts, bsums, row_start, N);
    scatter_kernel<<<(E + 255) / 256, 256, 0, stream>>>(src, dst, row_start, cursor, csr_src, E);
    aggregate_kernel<<<(N * 64 + 255) / 256, 256, 0, stream>>>(z_t, es_ed, csr_src, row_start, counts, out, N);
}

// Round 5
// 657.854 us; speedup vs baseline: 1.4380x; 1.2195x over previous
//
#include <hip/hip_runtime.h>
#include <math.h>

#define NEGV (-1000.0f)
#define SLOPE 0.01f
#define D_IN 256
#define LDK 72

typedef _Float16 half8 __attribute__((ext_vector_type(8)));
typedef _Float16 half4h __attribute__((ext_vector_type(4)));
typedef float f32x4 __attribute__((ext_vector_type(4)));

// ---------- W prep: W[h][k][f] fp32 -> split fp16 Wt_hi/Wt_lo[c][k], c=f*4+h ----------
__global__ void wprep_kernel(const float* __restrict__ W, _Float16* __restrict__ Wt_hi,
                             _Float16* __restrict__ Wt_lo) {
    int i = blockIdx.x * 256 + threadIdx.x;   // 65536, input-coalesced
    int f = i & 63;
    int k = (i >> 6) & 255;
    int h = i >> 14;
    float w = W[i];
    _Float16 hi = (_Float16)w;
    _Float16 lo = (_Float16)(w - (float)hi);
    int c = f * 4 + h;
    Wt_hi[c * 256 + k] = hi;
    Wt_lo[c * 256 + k] = lo;
}

// ---------- split-fp16 MFMA GEMM: z_t[n][c] = sum_k h[n][k]*Wt[c][k], fp32 out ----------
// BM=128, BN=128, BK=64; 512 thr = 8 waves; wave w: rows (w&3)*32 (2 tiles), cols (w>>2)*64 (4 tiles)
__global__ __launch_bounds__(512) void gemm_kernel(const float* __restrict__ hmat,
        const _Float16* __restrict__ Wt_hi, const _Float16* __restrict__ Wt_lo,
        float* __restrict__ z_t, int N) {
    __shared__ __align__(16) _Float16 smem[4 * 128 * LDK];   // 73728 B
    _Float16* A_hi = smem;
    _Float16* A_lo = smem + 128 * LDK;
    _Float16* B_hi = smem + 2 * 128 * LDK;
    _Float16* B_lo = smem + 3 * 128 * LDK;
    const int t = threadIdx.x;
    const int lane = t & 63;
    const int w = t >> 6;
    const int quad = lane >> 4;
    const int m16 = lane & 15;
    const int rg = w & 3;
    const int cg = w >> 2;
    const int n0 = (blockIdx.x >> 1) * 128;
    const int c0 = (blockIdx.x & 1) * 128;

    f32x4 acc[2][4];
#pragma unroll
    for (int rt = 0; rt < 2; rt++)
#pragma unroll
        for (int ct = 0; ct < 4; ct++) acc[rt][ct] = (f32x4){0.f, 0.f, 0.f, 0.f};

    for (int kc = 0; kc < 256; kc += 64) {
        __syncthreads();
        // stage A: 128 rows x 64 k, fp32 -> hi/lo fp16
#pragma unroll
        for (int i = 0; i < 4; i++) {
            int idx = i * 512 + t;                    // 0..2047
            int row = idx >> 4, q = idx & 15;
            int rr = min(n0 + row, N - 1);            // clamp; garbage rows masked at store
            float4 v = *(const float4*)&hmat[(size_t)rr * 256 + kc + q * 4];
            half4h hv, lv;
            hv[0] = (_Float16)v.x; lv[0] = (_Float16)(v.x - (float)hv[0]);
            hv[1] = (_Float16)v.y; lv[1] = (_Float16)(v.y - (float)hv[1]);
            hv[2] = (_Float16)v.z; lv[2] = (_Float16)(v.z - (float)hv[2]);
            hv[3] = (_Float16)v.w; lv[3] = (_Float16)(v.w - (float)hv[3]);
            *(half4h*)&A_hi[row * LDK + q * 4] = hv;
            *(half4h*)&A_lo[row * LDK + q * 4] = lv;
        }
        // stage B: 128 c x 64 k fp16 hi/lo
#pragma unroll
        for (int i = 0; i < 2; i++) {
            int idx = i * 512 + t;                    // 0..1023
            int c = idx >> 3, seg = idx & 7;
            float4 vh = *(const float4*)&Wt_hi[(c0 + c) * 256 + kc + seg * 8];
            float4 vl = *(const float4*)&Wt_lo[(c0 + c) * 256 + kc + seg * 8];
            *(float4*)&B_hi[c * LDK + seg * 8] = vh;
            *(float4*)&B_lo[c * LDK + seg * 8] = vl;
        }
        __syncthreads();
#pragma unroll
        for (int ks = 0; ks < 2; ks++) {
            half8 ah[2], al[2], bh[4], bl[4];
#pragma unroll
            for (int rt = 0; rt < 2; rt++) {
                int ro = ((rg * 2 + rt) * 16 + m16) * LDK + ks * 32 + quad * 8;
                ah[rt] = *(const half8*)&A_hi[ro];
                al[rt] = *(const half8*)&A_lo[ro];
            }
#pragma unroll
            for (int ct = 0; ct < 4; ct++) {
                int co = ((cg * 4 + ct) * 16 + m16) * LDK + ks * 32 + quad * 8;
                bh[ct] = *(const half8*)&B_hi[co];
                bl[ct] = *(const half8*)&B_lo[co];
            }
#pragma unroll
            for (int rt = 0; rt < 2; rt++)
#pragma unroll
                for (int ct = 0; ct < 4; ct++) {
                    acc[rt][ct] = __builtin_amdgcn_mfma_f32_16x16x32_f16(ah[rt], bh[ct], acc[rt][ct], 0, 0, 0);
                    acc[rt][ct] = __builtin_amdgcn_mfma_f32_16x16x32_f16(al[rt], bh[ct], acc[rt][ct], 0, 0, 0);
                    acc[rt][ct] = __builtin_amdgcn_mfma_f32_16x16x32_f16(ah[rt], bl[ct], acc[rt][ct], 0, 0, 0);
                }
        }
    }
    // epilogue: C/D col=lane&15, row=quad*4+reg; direct fp32 stores (16-lane coalesced)
#pragma unroll
    for (int rt = 0; rt < 2; rt++)
#pragma unroll
        for (int ct = 0; ct < 4; ct++)
#pragma unroll
            for (int r = 0; r < 4; r++) {
                int n = n0 + rg * 32 + rt * 16 + quad * 4 + r;
                int c = c0 + cg * 64 + ct * 16 + m16;
                if (n < N) z_t[(size_t)n * 256 + c] = acc[rt][ct][r];
            }
}

// ---------- es/ed per node (fp32 z) ----------
__global__ void esed_kernel(const float* __restrict__ z_t, const float* __restrict__ att,
                            float* __restrict__ es_ed, int N) {
    int gid = blockIdx.x * blockDim.x + threadIdx.x;
    int n = gid >> 6;
    int lane = gid & 63;
    if (n >= N) return;
    float4 zv = *(const float4*)&z_t[(size_t)n * 256 + lane * 4];
    float ps0 = zv.x * att[0 * 128 + lane];
    float ps1 = zv.y * att[1 * 128 + lane];
    float ps2 = zv.z * att[2 * 128 + lane];
    float ps3 = zv.w * att[3 * 128 + lane];
    float pd0 = zv.x * att[0 * 128 + 64 + lane];
    float pd1 = zv.y * att[1 * 128 + 64 + lane];
    float pd2 = zv.z * att[2 * 128 + 64 + lane];
    float pd3 = zv.w * att[3 * 128 + 64 + lane];
    for (int off = 1; off < 64; off <<= 1) {
        ps0 += __shfl_xor(ps0, off); ps1 += __shfl_xor(ps1, off);
        ps2 += __shfl_xor(ps2, off); ps3 += __shfl_xor(ps3, off);
        pd0 += __shfl_xor(pd0, off); pd1 += __shfl_xor(pd1, off);
        pd2 += __shfl_xor(pd2, off); pd3 += __shfl_xor(pd3, off);
    }
    if (lane == 0) {
        *(float4*)&es_ed[(size_t)n * 8]     = make_float4(ps0, ps1, ps2, ps3);
        *(float4*)&es_ed[(size_t)n * 8 + 4] = make_float4(pd0, pd1, pd2, pd3);
    }
}

// ---------- CSR build ----------
__global__ void hist_kernel(const int* __restrict__ dst, int* __restrict__ counts, int E) {
    int i = blockIdx.x * blockDim.x + threadIdx.x;
    if (i < E) atomicAdd(&counts[dst[i]], 1);
}

__global__ void scanA_kernel(const int* __restrict__ counts, int* __restrict__ bsums, int N) {
    __shared__ int lds[256];
    int t = threadIdx.x;
    int base = blockIdx.x * 1024 + t * 4;
    int s = 0;
    if (base + 3 < N) {
        int4 v = *(const int4*)&counts[base];
        s = v.x + v.y + v.z + v.w;
    } else {
        for (int u = 0; u < 4; u++) if (base + u < N) s += counts[base + u];
    }
    lds[t] = s; __syncthreads();
    for (int off = 128; off > 0; off >>= 1) {
        if (t < off) lds[t] += lds[t + off];
        __syncthreads();
    }
    if (t == 0) bsums[blockIdx.x] = lds[0];
}

__global__ void scanB_kernel(int* __restrict__ bsums, int nb) {
    __shared__ int lds[256];
    int t = threadIdx.x;
    int v = (t < nb) ? bsums[t] : 0;
    lds[t] = v; __syncthreads();
    for (int off = 1; off < 256; off <<= 1) {
        int x = (t >= off) ? lds[t - off] : 0;
        __syncthreads();
        lds[t] += x;
        __syncthreads();
    }
    if (t < nb) bsums[t] = lds[t] - v;   // exclusive
}

__global__ void scanC_kernel(const int* __restrict__ counts, const int* __restrict__ bsums,
                             int* __restrict__ row_start, int N) {
    __shared__ int lds[256];
    int t = threadIdx.x;
    int base = blockIdx.x * 1024 + t * 4;
    int4 v = make_int4(0, 0, 0, 0);
    if (base + 3 < N) v = *(const int4*)&counts[base];
    else {
        if (base + 0 < N) v.x = counts[base + 0];
        if (base + 1 < N) v.y = counts[base + 1];
        if (base + 2 < N) v.z = counts[base + 2];
    }
    int s = v.x + v.y + v.z + v.w;
    lds[t] = s; __syncthreads();
    for (int off = 1; off < 256; off <<= 1) {
        int x = (t >= off) ? lds[t - off] : 0;
        __syncthreads();
        lds[t] += x;
        __syncthreads();
    }
    int excl = lds[t] - s + bsums[blockIdx.x];
    int4 r;
    r.x = excl; r.y = r.x + v.x; r.z = r.y + v.y; r.w = r.z + v.z;
    if (base + 3 < N) *(int4*)&row_start[base] = r;
    else {
        if (base + 0 < N) row_start[base + 0] = r.x;
        if (base + 1 < N) row_start[base + 1] = r.y;
        if (base + 2 < N) row_start[base + 2] = r.z;
    }
}

__global__ void scatter_kernel(const int* __restrict__ src, const int* __restrict__ dst,
                               const int* __restrict__ row_start, int* __restrict__ cursor,
                               int* __restrict__ csr_src, int E) {
    int i = blockIdx.x * blockDim.x + threadIdx.x;
    if (i < E) {
        int d = dst[i];
        int pos = row_start[d] + atomicAdd(&cursor[d], 1);
        csr_src[pos] = src[i];
    }
}

// ---------- aggregation: one wave per node, online softmax, fp32 z gathers ----------
__global__ __launch_bounds__(256) void aggregate_kernel(const float* __restrict__ z_t,
        const float* __restrict__ es_ed, const int* __restrict__ csr_src,
        const int* __restrict__ row_start, const int* __restrict__ counts,
        float* __restrict__ out, int N) {
    int gid = blockIdx.x * blockDim.x + threadIdx.x;
    int n = gid >> 6;
    int lane = gid & 63;   // = f
    if (n >= N) return;
    int cnt = counts[n];
    int start = row_start[n];
    float4 edn = *(const float4*)&es_ed[(size_t)n * 8 + 4];

    float m0 = -INFINITY, m1 = -INFINITY, m2 = -INFINITY, m3 = -INFINITY;
    float l0 = 0.f, l1 = 0.f, l2 = 0.f, l3 = 0.f;
    float4 o = make_float4(0.f, 0.f, 0.f, 0.f);

    for (int base = 0; base < cnt; base += 64) {
        int c = min(64, cnt - base);
        int i = base + lane;
        int s = 0;
        float e0 = -INFINITY, e1 = -INFINITY, e2 = -INFINITY, e3 = -INFINITY;
        if (i < cnt) {
            s = csr_src[start + i];
            float4 esv = *(const float4*)&es_ed[(size_t)s * 8];
            float x0 = esv.x + edn.x; e0 = x0 > 0.f ? x0 : SLOPE * x0; if (e0 == 0.f) e0 = NEGV;
            float x1 = esv.y + edn.y; e1 = x1 > 0.f ? x1 : SLOPE * x1; if (e1 == 0.f) e1 = NEGV;
            float x2 = esv.z + edn.z; e2 = x2 > 0.f ? x2 : SLOPE * x2; if (e2 == 0.f) e2 = NEGV;
            float x3 = esv.w + edn.w; e3 = x3 > 0.f ? x3 : SLOPE * x3; if (e3 == 0.f) e3 = NEGV;
        }
        float c0 = e0, c1 = e1, c2 = e2, c3 = e3;
        for (int off = 1; off < 64; off <<= 1) {
            c0 = fmaxf(c0, __shfl_xor(c0, off)); c1 = fmaxf(c1, __shfl_xor(c1, off));
            c2 = fmaxf(c2, __shfl_xor(c2, off)); c3 = fmaxf(c3, __shfl_xor(c3, off));
        }
        float nm0 = fmaxf(m0, c0), nm1 = fmaxf(m1, c1), nm2 = fmaxf(m2, c2), nm3 = fmaxf(m3, c3);
        float sc0 = __expf(m0 - nm0), sc1 = __expf(m1 - nm1);
        float sc2 = __expf(m2 - nm2), sc3 = __expf(m3 - nm3);
        o.x *= sc0; o.y *= sc1; o.z *= sc2; o.w *= sc3;
        l0 *= sc0; l1 *= sc1; l2 *= sc2; l3 *= sc3;
        m0 = nm0; m1 = nm1; m2 = nm2; m3 = nm3;

        float p0 = 0.f, p1 = 0.f, p2 = 0.f, p3 = 0.f;
        if (i < cnt) {
            p0 = __expf(e0 - m0); p1 = __expf(e1 - m1);
            p2 = __expf(e2 - m2); p3 = __expf(e3 - m3);
        }
        l0 += p0; l1 += p1; l2 += p2; l3 += p3;

        int j = 0;
        for (; j + 7 < c; j += 8) {
            float4 pp[8]; float4 zz[8];
#pragma unroll
            for (int u = 0; u < 8; u++) {
                int sj = __shfl(s, j + u);
                pp[u] = make_float4(__shfl(p0, j + u), __shfl(p1, j + u),
                                    __shfl(p2, j + u), __shfl(p3, j + u));
                zz[u] = *(const float4*)&z_t[(size_t)sj * 256 + lane * 4];
            }
#pragma unroll
            for (int u = 0; u < 8; u++) {
                o.x += pp[u].x * zz[u].x; o.y += pp[u].y * zz[u].y;
                o.z += pp[u].z * zz[u].z; o.w += pp[u].w * zz[u].w;
            }
        }
        for (; j < c; ++j) {
            int sj = __shfl(s, j);
            float q0 = __shfl(p0, j), q1 = __shfl(p1, j), q2 = __shfl(p2, j), q3 = __shfl(p3, j);
            float4 zv = *(const float4*)&z_t[(size_t)sj * 256 + lane * 4];
            o.x += q0 * zv.x; o.y += q1 * zv.y; o.z += q2 * zv.z; o.w += q3 * zv.w;
        }
    }
    for (int off = 1; off < 64; off <<= 1) {
        l0 += __shfl_xor(l0, off); l1 += __shfl_xor(l1, off);
        l2 += __shfl_xor(l2, off); l3 += __shfl_xor(l3, off);
    }
    if (cnt > 0) { o.x /= l0; o.y /= l1; o.z /= l2; o.w /= l3; }
    size_t ob = (size_t)n * 256;
    __builtin_nontemporal_store(o.x, &out[ob + lane]);
    __builtin_nontemporal_store(o.y, &out[ob + 64 + lane]);
    __builtin_nontemporal_store(o.z, &out[ob + 128 + lane]);
    __builtin_nontemporal_store(o.w, &out[ob + 192 + lane]);
}

extern "C" void kernel_launch(void* const* d_in, const int* in_sizes, int n_in,
                              void* d_out, int out_size, void* d_ws, size_t ws_size,
                              hipStream_t stream) {
    const float* hmat = (const float*)d_in[0];
    const float* W    = (const float*)d_in[1];
    const float* att  = (const float*)d_in[2];
    const int*   src  = (const int*)d_in[3];
    const int*   dst  = (const int*)d_in[4];
    int N = in_sizes[0] / D_IN;
    int E = in_sizes[3];
    float* out = (float*)d_out;

    // workspace layout (16B-aligned); total ~114 MB
    float* z_t      = (float*)d_ws;                       // N*256 fp32
    float* es_ed    = z_t + (size_t)N * 256;              // N*8
    _Float16* Wt_hi = (_Float16*)(es_ed + (size_t)N * 8); // 65536 fp16
    _Float16* Wt_lo = Wt_hi + 65536;                      // 65536 fp16
    int*   counts   = (int*)(Wt_lo + 65536);              // N
    int*   cursor   = counts + N;                         // N (contiguous with counts)
    int*   row_start= cursor + N;                         // N
    int*   bsums    = row_start + N;                      // <=256
    int*   csr_src  = bsums + 256;                        // E

    int NB = (N + 1023) / 1024;

    hipMemsetAsync(counts, 0, (size_t)2 * N * sizeof(int), stream);
    wprep_kernel<<<256, 256, 0, stream>>>(W, Wt_hi, Wt_lo);
    gemm_kernel<<<((N + 127) / 128) * 2, 512, 0, stream>>>(hmat, Wt_hi, Wt_lo, z_t, N);
    esed_kernel<<<(N * 64 + 255) / 256, 256, 0, stream>>>(z_t, att, es_ed, N);
    hist_kernel<<<(E + 255) / 256, 256, 0, stream>>>(dst, counts, E);
    scanA_kernel<<<NB, 256, 0, stream>>>(counts, bsums, N);
    scanB_kernel<<<1, 256, 0, stream>>>(bsums, NB);
    scanC_kernel<<<NB, 256, 0, stream>>>(counts, bsums, row_start, N);
    scatter_kernel<<<(E + 255) / 256, 256, 0, stream>>>(src, dst, row_start, cursor, csr_src, E);
    aggregate_kernel<<<(N * 64 + 255) / 256, 256, 0, stream>>>(z_t, es_ed, csr_src, row_start, counts, out, N);
}